// Round 6
// baseline (251.065 us; speedup 1.0000x reference)
//
#include <hip/hip_runtime.h>
#include <stdint.h>

#define AS1 __attribute__((address_space(1)))
#define AS3 __attribute__((address_space(3)))

typedef __bf16 bf16x8 __attribute__((ext_vector_type(8)));
typedef float f32x4 __attribute__((ext_vector_type(4)));

constexpr int NB = 8;     // batches
constexpr int N  = 2048;  // nodes
constexpr int F  = 128;   // features (in == out)

__device__ __forceinline__ unsigned short bf16r(float f) {
    unsigned u = __float_as_uint(f);
    return (unsigned short)((u + 0x7FFFu + ((u >> 16) & 1u)) >> 16);
}
__device__ __forceinline__ float bf2f(unsigned short s) {
    return __uint_as_float(((unsigned)s) << 16);
}

// ---------------------------------------------------------------------------
// Wb2 element layout (MFMA-B-operand native, linear in k-chunks):
//   byte(b, n, o) = b*N*F*2 + (n>>3)*2048 + o*16 + (n&7)*2
// BK=64 chunk c = contiguous 16384 B at b*N*F*2 + c*16384.
// ---------------------------------------------------------------------------

// K1 (fused): Wh = h @ W^T;  e = Wh @ a2;  p = exp(e);
//   p16 = bf16(p);  Wb2 = bf16(bf2f(p16) * Wh)        [unchanged, proven]
__global__ __launch_bounds__(256) void k1_wh(const float* __restrict__ h,
                                             const float* __restrict__ W,
                                             const float* __restrict__ a,
                                             unsigned short* __restrict__ Wb2,
                                             unsigned short* __restrict__ p16) {
    __shared__ float epart[2][64];

    const int tid  = threadIdx.x;
    const int lane = tid & 63, wid = tid >> 6;
    const int quad = lane >> 4, l15 = lane & 15;
    const int wm = wid >> 1, wn = wid & 1;
    const int m0 = blockIdx.x * 64;
    const int batch = m0 >> 11;
    const int nbase = m0 & 2047;

    f32x4 acc[2][4] = {};

#pragma unroll
    for (int kk = 0; kk < 4; ++kk) {
        const int k = kk * 32 + quad * 8;
        bf16x8 afr[2], bfr[4];
#pragma unroll
        for (int rt = 0; rt < 2; ++rt) {
            const float* src = h + (size_t)(m0 + wm * 32 + rt * 16 + l15) * F + k;
            float4 x0 = *(const float4*)src;
            float4 x1 = *(const float4*)(src + 4);
            afr[rt][0] = (__bf16)x0.x; afr[rt][1] = (__bf16)x0.y;
            afr[rt][2] = (__bf16)x0.z; afr[rt][3] = (__bf16)x0.w;
            afr[rt][4] = (__bf16)x1.x; afr[rt][5] = (__bf16)x1.y;
            afr[rt][6] = (__bf16)x1.z; afr[rt][7] = (__bf16)x1.w;
        }
#pragma unroll
        for (int ct = 0; ct < 4; ++ct) {
            const int o = wn * 64 + ct * 16 + l15;
            const float* src = W + (size_t)o * F + k;
            float4 x0 = *(const float4*)src;
            float4 x1 = *(const float4*)(src + 4);
            bfr[ct][0] = (__bf16)x0.x; bfr[ct][1] = (__bf16)x0.y;
            bfr[ct][2] = (__bf16)x0.z; bfr[ct][3] = (__bf16)x0.w;
            bfr[ct][4] = (__bf16)x1.x; bfr[ct][5] = (__bf16)x1.y;
            bfr[ct][6] = (__bf16)x1.z; bfr[ct][7] = (__bf16)x1.w;
        }
#pragma unroll
        for (int rt = 0; rt < 2; ++rt)
#pragma unroll
            for (int ct = 0; ct < 4; ++ct)
                acc[rt][ct] = __builtin_amdgcn_mfma_f32_16x16x32_bf16(
                    afr[rt], bfr[ct], acc[rt][ct], 0, 0, 0);
    }

    float a2v[4];
#pragma unroll
    for (int ct = 0; ct < 4; ++ct) a2v[ct] = a[F + wn * 64 + ct * 16 + l15];

    float ep[2][4];
#pragma unroll
    for (int rt = 0; rt < 2; ++rt)
#pragma unroll
        for (int g = 0; g < 4; ++g) {
            float s = 0.f;
#pragma unroll
            for (int ct = 0; ct < 4; ++ct) s += acc[rt][ct][g] * a2v[ct];
            ep[rt][g] = s;
        }
#pragma unroll
    for (int m = 1; m < 16; m <<= 1)
#pragma unroll
        for (int rt = 0; rt < 2; ++rt)
#pragma unroll
            for (int g = 0; g < 4; ++g)
                ep[rt][g] += __shfl_xor(ep[rt][g], m);

    if (l15 == 0)
#pragma unroll
        for (int rt = 0; rt < 2; ++rt)
#pragma unroll
            for (int g = 0; g < 4; ++g)
                epart[wn][wm * 32 + rt * 16 + quad * 4 + g] = ep[rt][g];
    __syncthreads();

#pragma unroll
    for (int rt = 0; rt < 2; ++rt)
#pragma unroll
        for (int ct = 0; ct < 4; ++ct) {
            const int o  = wn * 64 + ct * 16 + l15;
            const int r0 = wm * 32 + rt * 16 + quad * 4;
            const int n0 = nbase + r0;
            ushort4 v;
#pragma unroll
            for (int g = 0; g < 4; ++g) {
                const float e  = epart[0][r0 + g] + epart[1][r0 + g];
                const float pf = bf2f(bf16r(expf(e)));
                (&v.x)[g] = bf16r(pf * acc[rt][ct][g]);
            }
            size_t off = (size_t)batch * N * F + (size_t)(n0 >> 3) * 1024 + o * 8 + (n0 & 7);
            *(ushort4*)&Wb2[off] = v;
        }

    if (tid < 64) {
        const float e = epart[0][tid] + epart[1][tid];
        p16[batch * N + nbase + tid] = bf16r(expf(e));
    }
}

// K3 v5: m201 template + occupancy. BM=16 rows/block, grid 1024, LDS 44 KB
// -> 3 blocks/CU = 12 waves/CU (was 2 blk / 8 waves: the R5 latency residual).
//   out[b][i][o] = (sum_j adj[b][i][j]*Wb2[j][o]) / (sum_j adj[b][i][j]*p[j])
// BK=64, 32 chunks, ring-2 block-shared buffers, compile-time indices, raw
// s_barrier, per-wave counted vmcnt BEFORE the barrier (own 5 loads/chunk:
// 1 A + 4 B per wave -> steady wait vmcnt(5) = 1 newer chunk in flight).
// Waves split the 128 o-cols: wid = o-quarter (32 cols); every wave reads all
// 16 A rows (A tile 4 KB, XOR-swizzled 16B granules: slot g of row r holds
// global granule g^r -> all reads <=2-way bank = free). Denominator MFMA
// duplicated per wave (1/chunk, trivial); divide in-register; final f32 out.
// b = blk&7 XCD-pins batch (Wb2 slice 512 KB + p16 4 KB L2-resident).
__global__ __launch_bounds__(256, 3) void k3_fused(const float* __restrict__ adj,
                                                   const unsigned short* __restrict__ Wb2,
                                                   const unsigned short* __restrict__ p16,
                                                   float* __restrict__ out) {
    __shared__ __align__(16) char Asm_[2][4096];    // 16 rows x 64 k f32, swizzled
    __shared__ __align__(16) char Bsm_[2][16384];   // 64 k x 128 o bf16, linear image
    __shared__ __align__(16) char Psm_[4096];       // 2048 x bf16

    const int tid  = threadIdx.x;
    const int lane = tid & 63, wid = tid >> 6;      // wid = o-quarter 0..3
    const int quad = lane >> 4, l15 = lane & 15;
    const int b  = blockIdx.x & 7;
    const int it = blockIdx.x >> 3;                 // 0..127
    const int i0 = it * 16;

    // A stage source (1 gll/wave/chunk): wave wid covers rows wid*4+(lane>>4);
    // granule slot (lane&15) receives global granule (lane&15)^row (16B each).
    const float* aSrc;
    {
        const int rl = wid * 4 + (lane >> 4);
        const int G  = (lane & 15) ^ rl;
        aSrc = adj + (size_t)b * N * N + (size_t)(i0 + rl) * N + G * 4;
    }
    // B stage source (4 gll/wave/chunk): linear 16 KB chunk image, wave's 4 KB.
    const char* bSrc = (const char*)Wb2 + (size_t)b * (N * F * 2)
                     + wid * 4096 + lane * 16;
    // p16 source (4 KB once, wave 0).
    const char* pSrc = (const char*)p16 + (size_t)b * N * 2 + lane * 16;

#define K3_STAGE(BI, C)                                                            \
    do {                                                                           \
        __builtin_amdgcn_global_load_lds((const AS1 void*)(aSrc + (C) * 64),       \
            (AS3 void*)(&Asm_[BI][wid * 1024]), 16, 0, 0);                         \
        __builtin_amdgcn_global_load_lds(                                          \
            (const AS1 void*)(bSrc + (size_t)(C) * 16384 + 0 * 1024),              \
            (AS3 void*)(&Bsm_[BI][wid * 4096 + 0 * 1024]), 16, 0, 0);              \
        __builtin_amdgcn_global_load_lds(                                          \
            (const AS1 void*)(bSrc + (size_t)(C) * 16384 + 1 * 1024),              \
            (AS3 void*)(&Bsm_[BI][wid * 4096 + 1 * 1024]), 16, 0, 0);              \
        __builtin_amdgcn_global_load_lds(                                          \
            (const AS1 void*)(bSrc + (size_t)(C) * 16384 + 2 * 1024),              \
            (AS3 void*)(&Bsm_[BI][wid * 4096 + 2 * 1024]), 16, 0, 0);              \
        __builtin_amdgcn_global_load_lds(                                          \
            (const AS1 void*)(bSrc + (size_t)(C) * 16384 + 3 * 1024),              \
            (AS3 void*)(&Bsm_[BI][wid * 4096 + 3 * 1024]), 16, 0, 0);              \
    } while (0)

    f32x4 acc0 = {}, acc1 = {};
    f32x4 dacc = {0.f, 0.f, 0.f, 0.f};

    // Prologue: p (wave 0 only; drained by chunk-0's vmcnt(5) since it is
    // oldest in that wave's queue), then fill the 2-deep ring.
    if (wid == 0) {
#pragma unroll
        for (int s = 0; s < 4; ++s)
            __builtin_amdgcn_global_load_lds((const AS1 void*)(pSrc + s * 1024),
                (AS3 void*)(&Psm_[s * 1024]), 16, 0, 0);
    }
    K3_STAGE(0, 0);
    K3_STAGE(1, 1);

#define K3_CHUNK(C, BI, WAITSTR, DOSTAGE)                                          \
    {                                                                              \
        asm volatile(WAITSTR ::: "memory");                                        \
        __builtin_amdgcn_s_barrier();                                              \
        __builtin_amdgcn_sched_barrier(0);                                         \
        const char* aB = &Asm_[BI][0];                                             \
        const char* bB = &Bsm_[BI][0];                                             \
        _Pragma("unroll")                                                          \
        for (int ks = 0; ks < 2; ++ks) {                                           \
            const int G0 = ks * 8 + quad * 2;                                      \
            f32x4 x0 = *(const f32x4*)(aB + l15 * 256 + (((G0 + 0) ^ l15) << 4));  \
            f32x4 x1 = *(const f32x4*)(aB + l15 * 256 + (((G0 + 1) ^ l15) << 4));  \
            bf16x8 af;                                                             \
            af[0] = (__bf16)x0[0]; af[1] = (__bf16)x0[1];                          \
            af[2] = (__bf16)x0[2]; af[3] = (__bf16)x0[3];                          \
            af[4] = (__bf16)x1[0]; af[5] = (__bf16)x1[1];                          \
            af[6] = (__bf16)x1[2]; af[7] = (__bf16)x1[3];                          \
            bf16x8 pv = *(const bf16x8*)(&Psm_[(C) * 128 + ks * 64 + quad * 16]);  \
            bf16x8 bf0 = *(const bf16x8*)(bB + (ks * 4 + quad) * 2048              \
                                          + (wid * 32 + 0)  * 16 + l15 * 16);      \
            bf16x8 bf1 = *(const bf16x8*)(bB + (ks * 4 + quad) * 2048              \
                                          + (wid * 32 + 16) * 16 + l15 * 16);      \
            acc0 = __builtin_amdgcn_mfma_f32_16x16x32_bf16(af, bf0, acc0, 0, 0, 0);\
            acc1 = __builtin_amdgcn_mfma_f32_16x16x32_bf16(af, bf1, acc1, 0, 0, 0);\
            dacc = __builtin_amdgcn_mfma_f32_16x16x32_bf16(af, pv,  dacc, 0, 0, 0);\
        }                                                                          \
        if (DOSTAGE) {                                                             \
            __builtin_amdgcn_s_barrier();                                          \
            __builtin_amdgcn_sched_barrier(0);                                     \
            K3_STAGE(BI, (C) + 2);                                                 \
        }                                                                          \
    }

    // Main: chunk c restages c+2 (c <= 29; last staged = 31). Ring index is
    // compile-time everywhere; steady-state wait = vmcnt(5); never 0 mid-loop.
    for (int c2 = 0; c2 < 30; c2 += 2) {
        K3_CHUNK(c2 + 0, 0, "s_waitcnt vmcnt(5)", 1)
        K3_CHUNK(c2 + 1, 1, "s_waitcnt vmcnt(5)", 1)
    }
    K3_CHUNK(30, 0, "s_waitcnt vmcnt(5)", 0)
    K3_CHUNK(31, 1, "s_waitcnt vmcnt(0)", 0)

#undef K3_CHUNK
#undef K3_STAGE

    // Epilogue: divide by per-row denominator (C/D row = quad*4+g holds the
    // matching dacc[g] in every lane) and store final f32.
#pragma unroll
    for (int g = 0; g < 4; ++g) {
        const float inv = 1.0f / dacc[g];
        float* orow = out + ((size_t)b * N + i0 + quad * 4 + g) * F
                    + wid * 32 + l15;
        orow[0]  = acc0[g] * inv;
        orow[16] = acc1[g] * inv;
    }
}

// ---------------------------------------------------------------------------
extern "C" void kernel_launch(void* const* d_in, const int* in_sizes, int n_in,
                              void* d_out, int out_size, void* d_ws, size_t ws_size,
                              hipStream_t stream) {
    const float* h   = (const float*)d_in[0];
    const float* adj = (const float*)d_in[1];
    const float* W   = (const float*)d_in[2];
    const float* a   = (const float*)d_in[3];
    float* out = (float*)d_out;

    unsigned short* Wb2 = (unsigned short*)d_ws;                        // 4 MB
    unsigned short* p16 = (unsigned short*)((char*)d_ws + (4u << 20));  // 32 KB

    k1_wh<<<NB * N / 64, 256, 0, stream>>>(h, W, a, Wb2, p16);
    k3_fused<<<NB * 128, 256, 0, stream>>>(adj, Wb2, p16, out);
}

// Round 7
// 217.490 us; speedup vs baseline: 1.1544x; 1.1544x over previous
//
#include <hip/hip_runtime.h>
#include <stdint.h>

#define AS1 __attribute__((address_space(1)))
#define AS3 __attribute__((address_space(3)))

typedef __bf16 bf16x8 __attribute__((ext_vector_type(8)));
typedef float f32x4 __attribute__((ext_vector_type(4)));

constexpr int NB = 8;     // batches
constexpr int N  = 2048;  // nodes
constexpr int F  = 128;   // features (in == out)

__device__ __forceinline__ unsigned short bf16r(float f) {
    unsigned u = __float_as_uint(f);
    return (unsigned short)((u + 0x7FFFu + ((u >> 16) & 1u)) >> 16);
}
__device__ __forceinline__ float bf2f(unsigned short s) {
    return __uint_as_float(((unsigned)s) << 16);
}

// ---------------------------------------------------------------------------
// Wb2 element layout (MFMA-B-operand native, linear in k-chunks):
//   byte(b, n, o) = b*N*F*2 + (n>>3)*2048 + o*16 + (n&7)*2
// BK=64 chunk c = contiguous 16384 B at b*N*F*2 + c*16384.
// ---------------------------------------------------------------------------

// K1 (fused): Wh = h @ W^T;  e = Wh @ a2;  p = exp(e);
//   p16 = bf16(p);  Wb2 = bf16(bf2f(p16) * Wh)        [unchanged, proven]
__global__ __launch_bounds__(256) void k1_wh(const float* __restrict__ h,
                                             const float* __restrict__ W,
                                             const float* __restrict__ a,
                                             unsigned short* __restrict__ Wb2,
                                             unsigned short* __restrict__ p16) {
    __shared__ float epart[2][64];

    const int tid  = threadIdx.x;
    const int lane = tid & 63, wid = tid >> 6;
    const int quad = lane >> 4, l15 = lane & 15;
    const int wm = wid >> 1, wn = wid & 1;
    const int m0 = blockIdx.x * 64;
    const int batch = m0 >> 11;
    const int nbase = m0 & 2047;

    f32x4 acc[2][4] = {};

#pragma unroll
    for (int kk = 0; kk < 4; ++kk) {
        const int k = kk * 32 + quad * 8;
        bf16x8 afr[2], bfr[4];
#pragma unroll
        for (int rt = 0; rt < 2; ++rt) {
            const float* src = h + (size_t)(m0 + wm * 32 + rt * 16 + l15) * F + k;
            float4 x0 = *(const float4*)src;
            float4 x1 = *(const float4*)(src + 4);
            afr[rt][0] = (__bf16)x0.x; afr[rt][1] = (__bf16)x0.y;
            afr[rt][2] = (__bf16)x0.z; afr[rt][3] = (__bf16)x0.w;
            afr[rt][4] = (__bf16)x1.x; afr[rt][5] = (__bf16)x1.y;
            afr[rt][6] = (__bf16)x1.z; afr[rt][7] = (__bf16)x1.w;
        }
#pragma unroll
        for (int ct = 0; ct < 4; ++ct) {
            const int o = wn * 64 + ct * 16 + l15;
            const float* src = W + (size_t)o * F + k;
            float4 x0 = *(const float4*)src;
            float4 x1 = *(const float4*)(src + 4);
            bfr[ct][0] = (__bf16)x0.x; bfr[ct][1] = (__bf16)x0.y;
            bfr[ct][2] = (__bf16)x0.z; bfr[ct][3] = (__bf16)x0.w;
            bfr[ct][4] = (__bf16)x1.x; bfr[ct][5] = (__bf16)x1.y;
            bfr[ct][6] = (__bf16)x1.z; bfr[ct][7] = (__bf16)x1.w;
        }
#pragma unroll
        for (int rt = 0; rt < 2; ++rt)
#pragma unroll
            for (int ct = 0; ct < 4; ++ct)
                acc[rt][ct] = __builtin_amdgcn_mfma_f32_16x16x32_bf16(
                    afr[rt], bfr[ct], acc[rt][ct], 0, 0, 0);
    }

    float a2v[4];
#pragma unroll
    for (int ct = 0; ct < 4; ++ct) a2v[ct] = a[F + wn * 64 + ct * 16 + l15];

    float ep[2][4];
#pragma unroll
    for (int rt = 0; rt < 2; ++rt)
#pragma unroll
        for (int g = 0; g < 4; ++g) {
            float s = 0.f;
#pragma unroll
            for (int ct = 0; ct < 4; ++ct) s += acc[rt][ct][g] * a2v[ct];
            ep[rt][g] = s;
        }
#pragma unroll
    for (int m = 1; m < 16; m <<= 1)
#pragma unroll
        for (int rt = 0; rt < 2; ++rt)
#pragma unroll
            for (int g = 0; g < 4; ++g)
                ep[rt][g] += __shfl_xor(ep[rt][g], m);

    if (l15 == 0)
#pragma unroll
        for (int rt = 0; rt < 2; ++rt)
#pragma unroll
            for (int g = 0; g < 4; ++g)
                epart[wn][wm * 32 + rt * 16 + quad * 4 + g] = ep[rt][g];
    __syncthreads();

#pragma unroll
    for (int rt = 0; rt < 2; ++rt)
#pragma unroll
        for (int ct = 0; ct < 4; ++ct) {
            const int o  = wn * 64 + ct * 16 + l15;
            const int r0 = wm * 32 + rt * 16 + quad * 4;
            const int n0 = nbase + r0;
            ushort4 v;
#pragma unroll
            for (int g = 0; g < 4; ++g) {
                const float e  = epart[0][r0 + g] + epart[1][r0 + g];
                const float pf = bf2f(bf16r(expf(e)));
                (&v.x)[g] = bf16r(pf * acc[rt][ct][g]);
            }
            size_t off = (size_t)batch * N * F + (size_t)(n0 >> 3) * 1024 + o * 8 + (n0 & 7);
            *(ushort4*)&Wb2[off] = v;
        }

    if (tid < 64) {
        const float e = epart[0][tid] + epart[1][tid];
        p16[batch * N + nbase + tid] = bf16r(expf(e));
    }
}

// K3 v6: BYTES ARE THE LEVER. All variants (R2-R6) pinned at 10-11.5 B/cyc/CU
// delivered VMEM -> per-CU byte budget determines time. v4 moved 395 MB
// (B re-read 268 MB = 2/3); this version: BM=64 rows/block, grid 256 (1 blk/CU,
// blk&7 = batch = XCD pin), 512 threads = 8 waves -> B re-read halves to 134 MB.
// Total ~280 MB ~= 1.08 MB/CU -> ~42 us at the measured ceiling.
//   out[b][i][o] = (sum_j adj[b][i][j]*Wb2[j][o]) / (sum_j adj[b][i][j]*p[j])
// Structure = v4's proven m201 semantics: BK=64, 32 chunks, ring-3 shared
// buffers (compile-time indices), 4 global_load_lds/wave/chunk (2 A + 2 B),
// own-loads counted vmcnt(8) BEFORE raw s_barrier (never 0 mid-loop), second
// barrier before restage (WAR-safe). LDS = 3x32 KB + p 4 KB = 100 KB (static
// >64 KB proven in R4's 76 KB run). Waves 2Mx4N: wr = 32-row half, wc = 32-col
// quarter; acc 2x2 tiles (16 VGPR) + dacc 2 (8 VGPR). A XOR-swizzled in 16B
// granules (slot g of row r holds granule g^(r&15) -> all LDS reads <=2-way
// bank = free); B staged linear (Wb2 image is MFMA-native). Denominator via
// MFMA vs p16 (dup x4 waves, trivial); divide in-register; final f32 out.
__global__ __launch_bounds__(512, 2) void k3_fused(const float* __restrict__ adj,
                                                   const unsigned short* __restrict__ Wb2,
                                                   const unsigned short* __restrict__ p16,
                                                   float* __restrict__ out) {
    __shared__ __align__(16) char Asm_[3][16384];   // 64 rows x 64 k f32, swizzled
    __shared__ __align__(16) char Bsm_[3][16384];   // 64 k x 128 o bf16, linear image
    __shared__ __align__(16) char Psm_[4096];       // 2048 x bf16

    const int tid  = threadIdx.x;
    const int lane = tid & 63, wid = tid >> 6;      // 8 waves
    const int quad = lane >> 4, l15 = lane & 15;
    const int wr = wid >> 2, wc = wid & 3;          // row-half / col-quarter
    const int b  = blockIdx.x & 7;
    const int it = blockIdx.x >> 3;                 // 0..31
    const int i0 = it * 64;

    // A stage sources (2 gll/wave/chunk): instr ii = wid*2+s covers rows
    // ii*4+(lane>>4); granule slot (lane&15) receives granule (lane&15)^(r&15).
    const float* aSrc[2];
#pragma unroll
    for (int s = 0; s < 2; ++s) {
        const int rl = (wid * 2 + s) * 4 + (lane >> 4);
        const int G  = (lane & 15) ^ (rl & 15);
        aSrc[s] = adj + (size_t)b * N * N + (size_t)(i0 + rl) * N + G * 4;
    }
    // B stage source (2 gll/wave/chunk): linear 16 KB chunk image, wave's 2 KB.
    const char* bSrc = (const char*)Wb2 + (size_t)b * (N * F * 2)
                     + wid * 2048 + lane * 16;
    // p16 source (4 KB once, wave 0).
    const char* pSrc = (const char*)p16 + (size_t)b * N * 2 + lane * 16;

#define K3_STAGE(BI, C)                                                            \
    do {                                                                           \
        __builtin_amdgcn_global_load_lds((const AS1 void*)(aSrc[0] + (C) * 64),    \
            (AS3 void*)(&Asm_[BI][(wid * 2 + 0) * 1024]), 16, 0, 0);               \
        __builtin_amdgcn_global_load_lds((const AS1 void*)(aSrc[1] + (C) * 64),    \
            (AS3 void*)(&Asm_[BI][(wid * 2 + 1) * 1024]), 16, 0, 0);               \
        __builtin_amdgcn_global_load_lds(                                          \
            (const AS1 void*)(bSrc + (size_t)(C) * 16384 + 0 * 1024),              \
            (AS3 void*)(&Bsm_[BI][wid * 2048 + 0 * 1024]), 16, 0, 0);              \
        __builtin_amdgcn_global_load_lds(                                          \
            (const AS1 void*)(bSrc + (size_t)(C) * 16384 + 1 * 1024),              \
            (AS3 void*)(&Bsm_[BI][wid * 2048 + 1 * 1024]), 16, 0, 0);              \
    } while (0)

    f32x4 acc[2][2] = {};
    f32x4 dacc[2] = {};

    // Prologue: p (wave 0; oldest in its queue, drained by chunk-0's vmcnt(8)),
    // then fill the 3-deep ring (12 gll/wave in flight).
    if (wid == 0) {
#pragma unroll
        for (int s = 0; s < 4; ++s)
            __builtin_amdgcn_global_load_lds((const AS1 void*)(pSrc + s * 1024),
                (AS3 void*)(&Psm_[s * 1024]), 16, 0, 0);
    }
    K3_STAGE(0, 0);
    K3_STAGE(1, 1);
    K3_STAGE(2, 2);

#define K3_CHUNK(C, BI, WAITSTR, DOSTAGE)                                          \
    {                                                                              \
        asm volatile(WAITSTR ::: "memory");                                        \
        __builtin_amdgcn_s_barrier();                                              \
        __builtin_amdgcn_sched_barrier(0);                                         \
        const char* aB = &Asm_[BI][0];                                             \
        const char* bB = &Bsm_[BI][0];                                             \
        _Pragma("unroll")                                                          \
        for (int ks = 0; ks < 2; ++ks) {                                           \
            bf16x8 pv = *(const bf16x8*)(&Psm_[(C) * 128 + ks * 64 + quad * 16]);  \
            bf16x8 af[2];                                                          \
            _Pragma("unroll")                                                      \
            for (int rt = 0; rt < 2; ++rt) {                                       \
                const int row = wr * 32 + rt * 16 + l15;                           \
                const int G0  = ks * 8 + quad * 2;                                 \
                f32x4 x0 = *(const f32x4*)(aB + row * 256                          \
                              + (((G0 + 0) ^ (row & 15)) << 4));                   \
                f32x4 x1 = *(const f32x4*)(aB + row * 256                          \
                              + (((G0 + 1) ^ (row & 15)) << 4));                   \
                af[rt][0] = (__bf16)x0[0]; af[rt][1] = (__bf16)x0[1];              \
                af[rt][2] = (__bf16)x0[2]; af[rt][3] = (__bf16)x0[3];              \
                af[rt][4] = (__bf16)x1[0]; af[rt][5] = (__bf16)x1[1];              \
                af[rt][6] = (__bf16)x1[2]; af[rt][7] = (__bf16)x1[3];              \
            }                                                                      \
            _Pragma("unroll")                                                      \
            for (int ct = 0; ct < 2; ++ct) {                                       \
                bf16x8 bf = *(const bf16x8*)(bB + (ks * 4 + quad) * 2048           \
                                + (wc * 32 + ct * 16) * 16 + l15 * 16);            \
                acc[0][ct] = __builtin_amdgcn_mfma_f32_16x16x32_bf16(              \
                    af[0], bf, acc[0][ct], 0, 0, 0);                               \
                acc[1][ct] = __builtin_amdgcn_mfma_f32_16x16x32_bf16(              \
                    af[1], bf, acc[1][ct], 0, 0, 0);                               \
            }                                                                      \
            dacc[0] = __builtin_amdgcn_mfma_f32_16x16x32_bf16(                     \
                af[0], pv, dacc[0], 0, 0, 0);                                      \
            dacc[1] = __builtin_amdgcn_mfma_f32_16x16x32_bf16(                     \
                af[1], pv, dacc[1], 0, 0, 0);                                      \
        }                                                                          \
        if (DOSTAGE) {                                                             \
            __builtin_amdgcn_s_barrier();                                          \
            __builtin_amdgcn_sched_barrier(0);                                     \
            K3_STAGE(BI, (C) + 3);                                                 \
        }                                                                          \
    }

    // Main: chunk c restages c+3 (c <= 28; last staged = 31). Ring index is
    // compile-time everywhere; steady-state wait = vmcnt(8) (= 2 newer chunks
    // x 4 own loads in flight); never drains to 0 mid-loop.
    for (int c3 = 0; c3 < 27; c3 += 3) {
        K3_CHUNK(c3 + 0, 0, "s_waitcnt vmcnt(8)", 1)
        K3_CHUNK(c3 + 1, 1, "s_waitcnt vmcnt(8)", 1)
        K3_CHUNK(c3 + 2, 2, "s_waitcnt vmcnt(8)", 1)
    }
    K3_CHUNK(27, 0, "s_waitcnt vmcnt(8)", 1)   // stages 30
    K3_CHUNK(28, 1, "s_waitcnt vmcnt(8)", 1)   // stages 31
    K3_CHUNK(29, 2, "s_waitcnt vmcnt(8)", 0)
    K3_CHUNK(30, 0, "s_waitcnt vmcnt(4)", 0)
    K3_CHUNK(31, 1, "s_waitcnt vmcnt(0)", 0)

#undef K3_CHUNK
#undef K3_STAGE

    // Epilogue: divide by per-row denominator (C/D row = quad*4+g holds the
    // matching dacc[rt][g] in every lane) and store final f32.
#pragma unroll
    for (int rt = 0; rt < 2; ++rt)
#pragma unroll
        for (int g = 0; g < 4; ++g) {
            const float inv = 1.0f / dacc[rt][g];
            float* orow = out + ((size_t)b * N + i0 + wr * 32 + rt * 16
                                 + quad * 4 + g) * F + wc * 32 + l15;
            orow[0]  = acc[rt][0][g] * inv;
            orow[16] = acc[rt][1][g] * inv;
        }
}

// ---------------------------------------------------------------------------
extern "C" void kernel_launch(void* const* d_in, const int* in_sizes, int n_in,
                              void* d_out, int out_size, void* d_ws, size_t ws_size,
                              hipStream_t stream) {
    const float* h   = (const float*)d_in[0];
    const float* adj = (const float*)d_in[1];
    const float* W   = (const float*)d_in[2];
    const float* a   = (const float*)d_in[3];
    float* out = (float*)d_out;

    unsigned short* Wb2 = (unsigned short*)d_ws;                        // 4 MB
    unsigned short* p16 = (unsigned short*)((char*)d_ws + (4u << 20));  // 32 KB

    k1_wh<<<NB * N / 64, 256, 0, stream>>>(h, W, a, Wb2, p16);
    k3_fused<<<NB * 32, 512, 0, stream>>>(adj, Wb2, p16, out);
}